// Round 3
// baseline (2442.313 us; speedup 1.0000x reference)
//
#include <hip/hip_runtime.h>

// SelfAttention: B=1, S_img=3072, S_txt=256, D=1920, H=30, hd=64. All I/O fp32.
// Internals: fp16 MFMA (mfma_f32_16x16x32_f16), fp32 accumulate.
constexpr int S_TOT  = 3328;
constexpr int S_TXT  = 256;
constexpr int DMODEL = 1920;
constexpr int NHEAD  = 30;
constexpr int HD     = 64;

typedef _Float16 half8 __attribute__((ext_vector_type(8)));
typedef float    f32x4 __attribute__((ext_vector_type(4)));
typedef float    f32x8 __attribute__((ext_vector_type(8)));

__device__ __forceinline__ f32x4 mfma16h(half8 a, half8 b, f32x4 c) {
    return __builtin_amdgcn_mfma_f32_16x16x32_f16(a, b, c, 0, 0, 0);
}
__device__ __forceinline__ half8 cvt8(const float* __restrict__ p) {
    f32x8 v = *(const f32x8*)p;
    half8 r;
    #pragma unroll
    for (int j = 0; j < 8; ++j) r[j] = (_Float16)v[j];
    return r;
}

// ---------------------------------------------------------------------------
// QKV projection fused with LN+RoPE (q,k) / transpose (v).
// Wave tile: 16 rows x 64 cols, n-block == one head (hd=64).
// q_h,k_h: [h][s][64] f16.  v_hT: [h][64][s] f16 (via LDS transpose).
// ---------------------------------------------------------------------------
__global__ __launch_bounds__(256) void gemm_qkv_fused(
    const float* __restrict__ hid, const float* __restrict__ enc,
    const float* __restrict__ Wq,  const float* __restrict__ Wk,
    const float* __restrict__ Wv,
    const float* __restrict__ bq,  const float* __restrict__ bk,
    const float* __restrict__ bv,
    const float* __restrict__ rcos, const float* __restrict__ rsin,
    _Float16* __restrict__ q_h, _Float16* __restrict__ k_h, _Float16* __restrict__ v_hT)
{
    const int tid  = threadIdx.x;
    const int wave = tid >> 6;
    const int lane = tid & 63;
    const int l16  = lane & 15;
    const int quad = lane >> 4;
    const int h    = blockIdx.y;
    const int z    = blockIdx.z;

    const float* W    = (z == 0) ? Wq : (z == 1) ? Wk : Wv;
    const float* bias = (z == 0) ? bq : (z == 1) ? bk : bv;

    const int m0 = blockIdx.x * 64 + wave * 16;
    const int n0 = h * HD;

    const int mrow = m0 + l16;
    const float* arow = (mrow < S_TXT) ? (enc + (size_t)mrow * DMODEL)
                                       : (hid + (size_t)(mrow - S_TXT) * DMODEL);
    const int koff = quad * 8;

    f32x4 acc[4];
    #pragma unroll
    for (int i = 0; i < 4; ++i) acc[i] = (f32x4){0.f, 0.f, 0.f, 0.f};

    for (int k0 = 0; k0 < DMODEL; k0 += 32) {
        half8 a = cvt8(arow + k0 + koff);
        #pragma unroll
        for (int i = 0; i < 4; ++i) {
            half8 b = cvt8(W + (size_t)(n0 + i * 16 + l16) * DMODEL + k0 + koff);
            acc[i] = mfma16h(a, b, acc[i]);
        }
    }

    __shared__ __attribute__((aligned(16))) _Float16 vlds[64][66];

    if (z < 2) {
        _Float16* dst = z ? k_h : q_h;
        const bool rope = (m0 >= S_TXT);          // uniform: S_TXT=256 = 4 blocks of 64
        #pragma unroll
        for (int r = 0; r < 4; ++r) {
            const int s = m0 + quad * 4 + r;
            float x[4], s1 = 0.f, s2 = 0.f;
            #pragma unroll
            for (int i = 0; i < 4; ++i) {
                x[i] = acc[i][r] + bias[n0 + i * 16 + l16];
                s1 += x[i];
                s2 += x[i] * x[i];
            }
            #pragma unroll
            for (int off = 1; off <= 8; off <<= 1) {
                s1 += __shfl_xor(s1, off);
                s2 += __shfl_xor(s2, off);
            }
            const float mu   = s1 * (1.f / 64.f);
            const float var  = fmaxf(s2 * (1.f / 64.f) - mu * mu, 0.f);
            const float rstd = rsqrtf(var + 1e-5f);
            float xn[4];
            #pragma unroll
            for (int i = 0; i < 4; ++i) xn[i] = (x[i] - mu) * rstd;
            float o[4];
            if (rope) {
                const int pos = s - S_TXT;
                #pragma unroll
                for (int i = 0; i < 4; ++i) {
                    const int d = i * 16 + l16;
                    const float c  = rcos[(size_t)pos * HD + d];
                    const float si = rsin[(size_t)pos * HD + d];
                    const float rot = (i < 2) ? -xn[i ^ 2] : xn[i ^ 2];
                    o[i] = xn[i] * c + rot * si;
                }
            } else {
                #pragma unroll
                for (int i = 0; i < 4; ++i) o[i] = xn[i];
            }
            #pragma unroll
            for (int i = 0; i < 4; ++i)
                dst[(size_t)(h * S_TOT + s) * HD + i * 16 + l16] = (_Float16)o[i];
        }
    } else {
        // V: no LN; stage into LDS, store transposed coalesced.
        #pragma unroll
        for (int r = 0; r < 4; ++r) {
            const int sl = wave * 16 + quad * 4 + r;
            #pragma unroll
            for (int i = 0; i < 4; ++i)
                vlds[sl][i * 16 + l16] = (_Float16)(acc[i][r] + bias[n0 + i * 16 + l16]);
        }
        __syncthreads();
        const int s0 = blockIdx.x * 64;
        #pragma unroll
        for (int e = 0; e < 16; ++e) {
            const int idx = e * 256 + tid;
            const int dd  = idx >> 6;      // 0..63
            const int sc  = idx & 63;      // consecutive per wave -> coalesced
            v_hT[(size_t)(h * HD + dd) * S_TOT + s0 + sc] = vlds[sc][dd];
        }
    }
}

// ---------------------------------------------------------------------------
// Flash attention: per wave = 16 q rows of one head; kv tiles of 64.
// ---------------------------------------------------------------------------
__global__ __launch_bounds__(256) void attn(
    const _Float16* __restrict__ q_h,
    const _Float16* __restrict__ k_h,
    const _Float16* __restrict__ v_hT,
    _Float16* __restrict__ aout)
{
    const int tid  = threadIdx.x;
    const int wave = tid >> 6;
    const int lane = tid & 63;
    const int l16  = lane & 15;
    const int quad = lane >> 4;
    const int h  = blockIdx.y;
    const int q0 = blockIdx.x * 64 + wave * 16;

    __shared__ __attribute__((aligned(16))) _Float16 p_lds[4][16][72];

    const _Float16* qbase = q_h + (size_t)(h * S_TOT + q0) * HD;
    const half8 aq0 = *(const half8*)(qbase + l16 * HD + quad * 8);
    const half8 aq1 = *(const half8*)(qbase + l16 * HD + 32 + quad * 8);

    const _Float16* kbase = k_h + (size_t)h * S_TOT * HD;
    const _Float16* vbase = v_hT + (size_t)h * HD * S_TOT;

    f32x4 o[4];
    #pragma unroll
    for (int i = 0; i < 4; ++i) o[i] = (f32x4){0.f, 0.f, 0.f, 0.f};
    float m_i[4] = {-1e30f, -1e30f, -1e30f, -1e30f};
    float l_i[4] = {0.f, 0.f, 0.f, 0.f};

    for (int kv0 = 0; kv0 < S_TOT; kv0 += 64) {
        // ---- scores S[16 q][64 kv] ----
        f32x4 sc[4];
        #pragma unroll
        for (int i = 0; i < 4; ++i) sc[i] = (f32x4){0.f, 0.f, 0.f, 0.f};
        #pragma unroll
        for (int i = 0; i < 4; ++i) {
            const _Float16* krow = kbase + (size_t)(kv0 + i * 16 + l16) * HD + quad * 8;
            half8 b0 = *(const half8*)(krow);
            half8 b1 = *(const half8*)(krow + 32);
            sc[i] = mfma16h(aq0, b0, sc[i]);
            sc[i] = mfma16h(aq1, b1, sc[i]);
        }
        // ---- online softmax: rows = quad*4+r, cols across {i, l16} ----
        #pragma unroll
        for (int r = 0; r < 4; ++r) {
            float mx = fmaxf(fmaxf(sc[0][r], sc[1][r]), fmaxf(sc[2][r], sc[3][r]));
            mx = fmaxf(mx, __shfl_xor(mx, 1));
            mx = fmaxf(mx, __shfl_xor(mx, 2));
            mx = fmaxf(mx, __shfl_xor(mx, 4));
            mx = fmaxf(mx, __shfl_xor(mx, 8));
            mx *= 0.125f;                                  // scale = 1/sqrt(64)
            const float mnew  = fmaxf(m_i[r], mx);
            const float alpha = __expf(m_i[r] - mnew);
            m_i[r] = mnew;
            float rs = 0.f;
            #pragma unroll
            for (int i = 0; i < 4; ++i) {
                float p = __expf(sc[i][r] * 0.125f - mnew);
                rs += p;
                p_lds[wave][quad * 4 + r][i * 16 + l16] = (_Float16)p;
            }
            rs += __shfl_xor(rs, 1);
            rs += __shfl_xor(rs, 2);
            rs += __shfl_xor(rs, 4);
            rs += __shfl_xor(rs, 8);
            l_i[r] = l_i[r] * alpha + rs;
            #pragma unroll
            for (int i = 0; i < 4; ++i) o[i][r] *= alpha;
        }
        __syncthreads();   // P stores visible + compiler fence before reads
        const half8 ap0 = *(const half8*)(&p_lds[wave][l16][quad * 8]);
        const half8 ap1 = *(const half8*)(&p_lds[wave][l16][32 + quad * 8]);
        #pragma unroll
        for (int i = 0; i < 4; ++i) {
            const _Float16* vrow = vbase + (size_t)(i * 16 + l16) * S_TOT + kv0 + quad * 8;
            half8 b0 = *(const half8*)(vrow);
            half8 b1 = *(const half8*)(vrow + 32);
            o[i] = mfma16h(ap0, b0, o[i]);
            o[i] = mfma16h(ap1, b1, o[i]);
        }
        __syncthreads();   // keep next tile's P stores behind these reads
    }
    // ---- epilogue: divide by l, write f16 [s][h*64+d] ----
    #pragma unroll
    for (int r = 0; r < 4; ++r) {
        const float inv = 1.f / l_i[r];
        const int srow = q0 + quad * 4 + r;
        #pragma unroll
        for (int i = 0; i < 4; ++i)
            aout[(size_t)srow * DMODEL + h * HD + i * 16 + l16] = (_Float16)(o[i][r] * inv);
    }
}

// ---------------------------------------------------------------------------
// Output projection + bias + row remap: d_out rows = [img(3072) | txt(256)], fp32
// ---------------------------------------------------------------------------
__global__ __launch_bounds__(256) void gemm_out(
    const _Float16* __restrict__ A,    // attn output [3328][1920] f16
    const float* __restrict__ Wo,
    const float* __restrict__ bo,
    float* __restrict__ out)
{
    const int tid  = threadIdx.x;
    const int wave = tid >> 6;
    const int lane = tid & 63;
    const int l16  = lane & 15;
    const int quad = lane >> 4;

    const int m0 = blockIdx.x * 64 + wave * 16;
    const int n0 = blockIdx.y * 64;

    const _Float16* arow = A + (size_t)(m0 + l16) * DMODEL;
    const int koff = quad * 8;

    f32x4 acc[4];
    #pragma unroll
    for (int i = 0; i < 4; ++i) acc[i] = (f32x4){0.f, 0.f, 0.f, 0.f};

    for (int k0 = 0; k0 < DMODEL; k0 += 32) {
        half8 a = *(const half8*)(arow + k0 + koff);
        #pragma unroll
        for (int i = 0; i < 4; ++i) {
            half8 b = cvt8(Wo + (size_t)(n0 + i * 16 + l16) * DMODEL + k0 + koff);
            acc[i] = mfma16h(a, b, acc[i]);
        }
    }
    #pragma unroll
    for (int i = 0; i < 4; ++i) {
        const int n = n0 + i * 16 + l16;
        const float bb = bo[n];
        #pragma unroll
        for (int r = 0; r < 4; ++r) {
            const int m = m0 + quad * 4 + r;
            const int orow = (m >= S_TXT) ? (m - S_TXT) : (m + 3072);
            out[(size_t)orow * DMODEL + n] = acc[i][r] + bb;
        }
    }
}

// ---------------------------------------------------------------------------
extern "C" void kernel_launch(void* const* d_in, const int* in_sizes, int n_in,
                              void* d_out, int out_size, void* d_ws, size_t ws_size,
                              hipStream_t stream) {
    const float* hid  = (const float*)d_in[0];
    const float* enc  = (const float*)d_in[1];
    const float* rcos = (const float*)d_in[2];
    const float* rsin = (const float*)d_in[3];
    const float* Wq   = (const float*)d_in[4];
    const float* bq   = (const float*)d_in[5];
    const float* Wk   = (const float*)d_in[6];
    const float* bk   = (const float*)d_in[7];
    const float* Wv   = (const float*)d_in[8];
    const float* bv   = (const float*)d_in[9];
    const float* Wo   = (const float*)d_in[10];
    const float* bo   = (const float*)d_in[11];

    char* ws = (char*)d_ws;
    _Float16* q_h  = (_Float16*)(ws + 0);           // 30*3328*64*2 = 12,779,520 B each
    _Float16* k_h  = (_Float16*)(ws + 12779520);
    _Float16* v_hT = (_Float16*)(ws + 25559040);
    _Float16* aout = (_Float16*)(ws + 38338560);    // 3328*1920*2
    // total ws use: 51,118,080 B

    gemm_qkv_fused<<<dim3(52, NHEAD, 3), 256, 0, stream>>>(
        hid, enc, Wq, Wk, Wv, bq, bk, bv, rcos, rsin, q_h, k_h, v_hT);
    attn<<<dim3(52, NHEAD), 256, 0, stream>>>(q_h, k_h, v_hT, aout);
    gemm_out<<<dim3(52, NHEAD), 256, 0, stream>>>(aout, Wo, bo, (float*)d_out);
}

// Round 5
// 710.112 us; speedup vs baseline: 3.4393x; 3.4393x over previous
//
#include <hip/hip_runtime.h>

// SelfAttention: B=1, S_img=3072, S_txt=256, D=1920, H=30, hd=64. All I/O fp32.
// Internals: fp16 MFMA (mfma_f32_16x16x32_f16), fp32 accumulate.
constexpr int S_TOT  = 3328;
constexpr int S_TXT  = 256;
constexpr int DMODEL = 1920;
constexpr int NHEAD  = 30;
constexpr int HD     = 64;

typedef _Float16 half8 __attribute__((ext_vector_type(8)));
typedef _Float16 half4v __attribute__((ext_vector_type(4)));
typedef float    f32x4 __attribute__((ext_vector_type(4)));

__device__ __forceinline__ f32x4 mfma16h(half8 a, half8 b, f32x4 c) {
    return __builtin_amdgcn_mfma_f32_16x16x32_f16(a, b, c, 0, 0, 0);
}
// async global->LDS, 16B per lane; lds dst = wave-uniform base + lane*16
__device__ __forceinline__ void gload16(void* lds, const void* g) {
    __builtin_amdgcn_global_load_lds(
        (const __attribute__((address_space(1))) void*)g,
        (__attribute__((address_space(3))) void*)lds, 16, 0, 0);
}

// ---------------------------------------------------------------------------
// fp32 -> fp16 converts: seg 0=enc,1=hid -> xh; 2..4 = Wq,Wk,Wv -> Wh(stacked)
// ---------------------------------------------------------------------------
__global__ __launch_bounds__(256) void cvt5(
    const float* __restrict__ hid, const float* __restrict__ enc,
    const float* __restrict__ Wq, const float* __restrict__ Wk,
    const float* __restrict__ Wv,
    _Float16* __restrict__ xh, _Float16* __restrict__ Wh)
{
    const int seg = blockIdx.y;
    const float* src; _Float16* dst; int n;
    switch (seg) {
        case 0:  src = enc; dst = xh;                    n = S_TXT * DMODEL;  break;
        case 1:  src = hid; dst = xh + S_TXT * DMODEL;   n = 3072 * DMODEL;   break;
        case 2:  src = Wq;  dst = Wh;                    n = DMODEL * DMODEL; break;
        case 3:  src = Wk;  dst = Wh + DMODEL * DMODEL;  n = DMODEL * DMODEL; break;
        default: src = Wv;  dst = Wh + 2 * DMODEL * DMODEL; n = DMODEL * DMODEL; break;
    }
    for (int i = (blockIdx.x * 256 + threadIdx.x) * 4; i < n; i += gridDim.x * 256 * 4) {
        float4 v = *(const float4*)(src + i);
        half4v h = {(_Float16)v.x, (_Float16)v.y, (_Float16)v.z, (_Float16)v.w};
        *(half4v*)(dst + i) = h;
    }
}

__global__ __launch_bounds__(256) void cvt_wo(const float* __restrict__ Wo,
                                              _Float16* __restrict__ Woh)
{
    const int n = DMODEL * DMODEL;
    for (int i = (blockIdx.x * 256 + threadIdx.x) * 4; i < n; i += gridDim.x * 256 * 4) {
        float4 v = *(const float4*)(Wo + i);
        half4v h = {(_Float16)v.x, (_Float16)v.y, (_Float16)v.z, (_Float16)v.w};
        *(half4v*)(Woh + i) = h;
    }
}

// ---------------------------------------------------------------------------
// QKV GEMM (m97 structure): 128x128 tile, BK=32, global_load_lds staging.
// N = 5760 (q|k|v stacked). Epilogue: LN(+RoPE, q*0.125) for z<2; V-transpose z=2.
// LDS: As[128][32] | Bs[128][32] (16 KB), unioned with vT[4][64][72] (36.9 KB).
// ---------------------------------------------------------------------------
__global__ __launch_bounds__(256) void gemm_qkv(
    const _Float16* __restrict__ xh,   // [3328][1920]
    const _Float16* __restrict__ Wh,   // [5760][1920]
    const float* __restrict__ bq, const float* __restrict__ bk,
    const float* __restrict__ bv,
    const float* __restrict__ rcos, const float* __restrict__ rsin,
    _Float16* __restrict__ q_h, _Float16* __restrict__ k_h,
    _Float16* __restrict__ v_hT)
{
    extern __shared__ __attribute__((aligned(16))) char smem[];
    _Float16* As = (_Float16*)smem;             // 128*32
    _Float16* Bs = (_Float16*)(smem + 8192);    // 128*32

    const int tid  = threadIdx.x;
    const int wave = tid >> 6;
    const int lane = tid & 63;
    const int l16  = lane & 15;
    const int quad = lane >> 4;

    const int m0  = blockIdx.x * 128;
    const int n0g = blockIdx.y * 128;
    const int z   = n0g / DMODEL;           // 0=q 1=k 2=v (block-uniform; 128|1920)
    const int nloc = n0g - z * DMODEL;

    const int wm = (wave >> 1) * 64;
    const int wn = (wave & 1) * 64;

    // staging pointers: each wave stages 32 rows of A and B (2 insts each)
    const _Float16* gA = xh + (size_t)(m0 + wave * 32 + (lane >> 2)) * DMODEL + ((lane & 3) << 3);
    const _Float16* gB = Wh + (size_t)(n0g + wave * 32 + (lane >> 2)) * DMODEL + ((lane & 3) << 3);
    _Float16* lA = As + wave * 32 * 32;
    _Float16* lB = Bs + wave * 32 * 32;

    f32x4 acc[4][4];
    #pragma unroll
    for (int j = 0; j < 4; ++j)
        #pragma unroll
        for (int i = 0; i < 4; ++i) acc[j][i] = (f32x4){0.f, 0.f, 0.f, 0.f};

    for (int k0 = 0; k0 < DMODEL; k0 += 32) {
        __syncthreads();
        gload16(lA,        gA + k0);
        gload16(lA + 512,  gA + 16 * DMODEL + k0);
        gload16(lB,        gB + k0);
        gload16(lB + 512,  gB + 16 * DMODEL + k0);
        __syncthreads();
        half8 af[4], bf[4];
        #pragma unroll
        for (int j = 0; j < 4; ++j)
            af[j] = *(const half8*)(As + (wm + j * 16 + l16) * 32 + quad * 8);
        #pragma unroll
        for (int i = 0; i < 4; ++i)
            bf[i] = *(const half8*)(Bs + (wn + i * 16 + l16) * 32 + quad * 8);
        #pragma unroll
        for (int j = 0; j < 4; ++j)
            #pragma unroll
            for (int i = 0; i < 4; ++i)
                acc[j][i] = mfma16h(af[j], bf[i], acc[j][i]);
    }
    __syncthreads();   // staging LDS dead; vT may reuse it (z==2)

    const int h = (nloc + wn) / 64;        // head for this wave's 64 cols

    if (z < 2) {
        const float* bias = z ? bk : bq;
        _Float16* dst = z ? k_h : q_h;
        const float qscale = z ? 1.f : 0.125f;      // fold 1/sqrt(64) into q
        const bool rope = (m0 >= S_TXT);            // block-uniform (128|256)
        #pragma unroll
        for (int j = 0; j < 4; ++j) {
            #pragma unroll
            for (int r = 0; r < 4; ++r) {
                const int s = m0 + wm + j * 16 + quad * 4 + r;
                float x[4], s1 = 0.f, s2 = 0.f;
                #pragma unroll
                for (int i = 0; i < 4; ++i) {
                    x[i] = acc[j][i][r] + bias[nloc + wn + i * 16 + l16];
                    s1 += x[i];
                    s2 += x[i] * x[i];
                }
                #pragma unroll
                for (int off = 1; off <= 8; off <<= 1) {
                    s1 += __shfl_xor(s1, off);
                    s2 += __shfl_xor(s2, off);
                }
                const float mu   = s1 * (1.f / 64.f);
                const float var  = fmaxf(s2 * (1.f / 64.f) - mu * mu, 0.f);
                const float rstd = rsqrtf(var + 1e-5f);
                float xn[4];
                #pragma unroll
                for (int i = 0; i < 4; ++i) xn[i] = (x[i] - mu) * rstd;
                float o[4];
                if (rope) {
                    const int pos = s - S_TXT;
                    #pragma unroll
                    for (int i = 0; i < 4; ++i) {
                        const int d = i * 16 + l16;
                        const float c  = rcos[(size_t)pos * HD + d];
                        const float si = rsin[(size_t)pos * HD + d];
                        const float rot = (i < 2) ? -xn[i ^ 2] : xn[i ^ 2];
                        o[i] = xn[i] * c + rot * si;
                    }
                } else {
                    #pragma unroll
                    for (int i = 0; i < 4; ++i) o[i] = xn[i];
                }
                #pragma unroll
                for (int i = 0; i < 4; ++i)
                    dst[(size_t)(h * S_TOT + s) * HD + i * 16 + l16] = (_Float16)(o[i] * qscale);
            }
        }
    } else {
        // V: transpose via wave-local LDS region, coalesced 16B stores.
        _Float16* vt = (_Float16*)smem + wave * 64 * 72;   // [64 d][72 pad]
        #pragma unroll
        for (int j = 0; j < 4; ++j)
            #pragma unroll
            for (int r = 0; r < 4; ++r)
                #pragma unroll
                for (int i = 0; i < 4; ++i)
                    vt[(i * 16 + l16) * 72 + j * 16 + quad * 4 + r] =
                        (_Float16)(acc[j][i][r] + bv[nloc + wn + i * 16 + l16]);
        __asm__ volatile("" ::: "memory");   // order LDS writes before reads (same wave)
        const int dl = lane >> 3;
        const int sl = (lane & 7) << 3;
        #pragma unroll
        for (int t = 0; t < 8; ++t) {
            const int d = t * 8 + dl;
            half8 vv = *(const half8*)(vt + d * 72 + sl);
            *(half8*)(v_hT + (size_t)(h * HD + d) * S_TOT + m0 + wm + sl) = vv;
        }
    }
}

// ---------------------------------------------------------------------------
// Flash attention with online softmax: per block 64 q rows of one head;
// kv tiles of 64 staged block-wide via global_load_lds (K and V^T, 2KB/wave each).
// LDS: Ks[64][64] | Vs[64][64] | Pl[4][16][72] = 25600 B.
// ---------------------------------------------------------------------------
__global__ __launch_bounds__(256) void attn(
    const _Float16* __restrict__ q_h,
    const _Float16* __restrict__ k_h,
    const _Float16* __restrict__ v_hT,
    _Float16* __restrict__ aout)
{
    extern __shared__ __attribute__((aligned(16))) char smem[];
    _Float16* Ks = (_Float16*)smem;              // [64 kv][64 d]
    _Float16* Vs = (_Float16*)(smem + 8192);     // [64 d][64 kv]
    _Float16* Pl = (_Float16*)(smem + 16384);    // [4][16][72]

    const int tid  = threadIdx.x;
    const int wave = tid >> 6;
    const int lane = tid & 63;
    const int l16  = lane & 15;
    const int quad = lane >> 4;
    const int h  = blockIdx.y;
    const int q0 = blockIdx.x * 64 + wave * 16;

    const _Float16* qbase = q_h + (size_t)(h * S_TOT + q0) * HD;
    const half8 aq0 = *(const half8*)(qbase + l16 * HD + quad * 8);
    const half8 aq1 = *(const half8*)(qbase + l16 * HD + 32 + quad * 8);

    const _Float16* kbase = k_h + (size_t)h * S_TOT * HD;
    const _Float16* vbase = v_hT + (size_t)h * HD * S_TOT;

    // staging: per wave 2 insts K (8 rows x 64 halves each) + 2 insts V
    const _Float16* gK0 = kbase + (size_t)(wave * 16 + (lane >> 3)) * HD + ((lane & 7) << 3);
    const _Float16* gK1 = gK0 + 8 * HD;
    _Float16* lK0 = Ks + (wave * 16) * 64;
    _Float16* lK1 = Ks + (wave * 16 + 8) * 64;
    const _Float16* gV0 = vbase + (size_t)(wave * 16 + (lane >> 3)) * S_TOT + ((lane & 7) << 3);
    const _Float16* gV1 = gV0 + 8 * S_TOT;
    _Float16* lV0 = Vs + (wave * 16) * 64;
    _Float16* lV1 = Vs + (wave * 16 + 8) * 64;

    f32x4 o[4];
    #pragma unroll
    for (int i = 0; i < 4; ++i) o[i] = (f32x4){0.f, 0.f, 0.f, 0.f};
    float m_i[4] = {-1e30f, -1e30f, -1e30f, -1e30f};
    float l_i[4] = {0.f, 0.f, 0.f, 0.f};

    for (int kv0 = 0; kv0 < S_TOT; kv0 += 64) {
        __syncthreads();
        gload16(lK0, gK0 + (size_t)kv0 * HD);
        gload16(lK1, gK1 + (size_t)kv0 * HD);
        gload16(lV0, gV0 + kv0);
        gload16(lV1, gV1 + kv0);
        __syncthreads();
        // ---- scores (q pre-scaled by 1/8) ----
        f32x4 sc[4];
        #pragma unroll
        for (int i = 0; i < 4; ++i) {
            sc[i] = (f32x4){0.f, 0.f, 0.f, 0.f};
            half8 b0 = *(const half8*)(Ks + (i * 16 + l16) * 64 + quad * 8);
            half8 b1 = *(const half8*)(Ks + (i * 16 + l16) * 64 + 32 + quad * 8);
            sc[i] = mfma16h(aq0, b0, sc[i]);
            sc[i] = mfma16h(aq1, b1, sc[i]);
        }
        // ---- online softmax: rows = quad*4+r, cols across {i, l16} ----
        #pragma unroll
        for (int r = 0; r < 4; ++r) {
            float mx = fmaxf(fmaxf(sc[0][r], sc[1][r]), fmaxf(sc[2][r], sc[3][r]));
            mx = fmaxf(mx, __shfl_xor(mx, 1));
            mx = fmaxf(mx, __shfl_xor(mx, 2));
            mx = fmaxf(mx, __shfl_xor(mx, 4));
            mx = fmaxf(mx, __shfl_xor(mx, 8));
            const float mnew  = fmaxf(m_i[r], mx);
            const float alpha = __expf(m_i[r] - mnew);
            m_i[r] = mnew;
            float rs = 0.f;
            #pragma unroll
            for (int i = 0; i < 4; ++i) {
                float p = __expf(sc[i][r] - mnew);
                rs += p;
                Pl[(wave * 16 + quad * 4 + r) * 72 + i * 16 + l16] = (_Float16)p;
            }
            rs += __shfl_xor(rs, 1);
            rs += __shfl_xor(rs, 2);
            rs += __shfl_xor(rs, 4);
            rs += __shfl_xor(rs, 8);
            l_i[r] = l_i[r] * alpha + rs;
            #pragma unroll
            for (int i = 0; i < 4; ++i) o[i][r] *= alpha;
        }
        __asm__ volatile("" ::: "memory");   // order P writes before reads (same wave)
        const half8 ap0 = *(const half8*)(Pl + (wave * 16 + l16) * 72 + quad * 8);
        const half8 ap1 = *(const half8*)(Pl + (wave * 16 + l16) * 72 + 32 + quad * 8);
        // ---- PV ----
        #pragma unroll
        for (int i = 0; i < 4; ++i) {
            half8 b0 = *(const half8*)(Vs + (i * 16 + l16) * 64 + quad * 8);
            half8 b1 = *(const half8*)(Vs + (i * 16 + l16) * 64 + 32 + quad * 8);
            o[i] = mfma16h(ap0, b0, o[i]);
            o[i] = mfma16h(ap1, b1, o[i]);
        }
    }
    #pragma unroll
    for (int r = 0; r < 4; ++r) {
        const float inv = 1.f / l_i[r];
        const int srow = q0 + quad * 4 + r;
        #pragma unroll
        for (int i = 0; i < 4; ++i)
            aout[(size_t)srow * DMODEL + h * HD + i * 16 + l16] = (_Float16)(o[i][r] * inv);
    }
}

// ---------------------------------------------------------------------------
// Out projection (m97 structure) + bias + row remap, fp32 out.
// ---------------------------------------------------------------------------
__global__ __launch_bounds__(256) void gemm_out(
    const _Float16* __restrict__ A,    // [3328][1920] f16
    const _Float16* __restrict__ Woh,  // [1920][1920] f16
    const float* __restrict__ bo,
    float* __restrict__ out)
{
    extern __shared__ __attribute__((aligned(16))) char smem[];
    _Float16* As = (_Float16*)smem;
    _Float16* Bs = (_Float16*)(smem + 8192);

    const int tid  = threadIdx.x;
    const int wave = tid >> 6;
    const int lane = tid & 63;
    const int l16  = lane & 15;
    const int quad = lane >> 4;

    const int m0 = blockIdx.x * 128;
    const int n0 = blockIdx.y * 128;
    const int wm = (wave >> 1) * 64;
    const int wn = (wave & 1) * 64;

    const _Float16* gA = A   + (size_t)(m0 + wave * 32 + (lane >> 2)) * DMODEL + ((lane & 3) << 3);
    const _Float16* gB = Woh + (size_t)(n0 + wave * 32 + (lane >> 2)) * DMODEL + ((lane & 3) << 3);
    _Float16* lA = As + wave * 32 * 32;
    _Float16* lB = Bs + wave * 32 * 32;

    f32x4 acc[4][4];
    #pragma unroll
    for (int j = 0; j < 4; ++j)
        #pragma unroll
        for (int i = 0; i < 4; ++i) acc[j][i] = (f32x4){0.f, 0.f, 0.f, 0.f};

    for (int k0 = 0; k0 < DMODEL; k0 += 32) {
        __syncthreads();
        gload16(lA,        gA + k0);
        gload16(lA + 512,  gA + 16 * DMODEL + k0);
        gload16(lB,        gB + k0);
        gload16(lB + 512,  gB + 16 * DMODEL + k0);
        __syncthreads();
        half8 af[4], bf[4];
        #pragma unroll
        for (int j = 0; j < 4; ++j)
            af[j] = *(const half8*)(As + (wm + j * 16 + l16) * 32 + quad * 8);
        #pragma unroll
        for (int i = 0; i < 4; ++i)
            bf[i] = *(const half8*)(Bs + (wn + i * 16 + l16) * 32 + quad * 8);
        #pragma unroll
        for (int j = 0; j < 4; ++j)
            #pragma unroll
            for (int i = 0; i < 4; ++i)
                acc[j][i] = mfma16h(af[j], bf[i], acc[j][i]);
    }
    #pragma unroll
    for (int j = 0; j < 4; ++j) {
        #pragma unroll
        for (int i = 0; i < 4; ++i) {
            const int n = n0 + wn + i * 16 + l16;
            const float bb = bo[n];
            #pragma unroll
            for (int r = 0; r < 4; ++r) {
                const int m = m0 + wm + j * 16 + quad * 4 + r;
                const int orow = (m >= S_TXT) ? (m - S_TXT) : (m + 3072);
                out[(size_t)orow * DMODEL + n] = acc[j][i][r] + bb;
            }
        }
    }
}

// ---------------------------------------------------------------------------
extern "C" void kernel_launch(void* const* d_in, const int* in_sizes, int n_in,
                              void* d_out, int out_size, void* d_ws, size_t ws_size,
                              hipStream_t stream) {
    const float* hid  = (const float*)d_in[0];
    const float* enc  = (const float*)d_in[1];
    const float* rcos = (const float*)d_in[2];
    const float* rsin = (const float*)d_in[3];
    const float* Wq   = (const float*)d_in[4];
    const float* bq   = (const float*)d_in[5];
    const float* Wk   = (const float*)d_in[6];
    const float* bk   = (const float*)d_in[7];
    const float* Wv   = (const float*)d_in[8];
    const float* bv   = (const float*)d_in[9];
    const float* Wo   = (const float*)d_in[10];
    const float* bo   = (const float*)d_in[11];

    // ws layout (proven 51.1 MB footprint):
    //   [0, 12.78M)   xh, later aout
    //   [12.78M, ...) q_h, later Woh
    //   [25.56M, ...) k_h
    //   [38.34M, ...) v_hT
    // d_out (25.6 MB fp32) doubles as Wh (22.1 MB fp16) until gemm_out writes it.
    char* ws = (char*)d_ws;
    _Float16* xh   = (_Float16*)(ws + 0);
    _Float16* aout = (_Float16*)(ws + 0);
    _Float16* q_h  = (_Float16*)(ws + 12779520);
    _Float16* Woh  = (_Float16*)(ws + 12779520);
    _Float16* k_h  = (_Float16*)(ws + 25559040);
    _Float16* v_hT = (_Float16*)(ws + 38338560);
    _Float16* Wh   = (_Float16*)d_out;

    cvt5<<<dim3(128, 5), 256, 0, stream>>>(hid, enc, Wq, Wk, Wv, xh, Wh);
    gemm_qkv<<<dim3(26, 45), 256, 36864, stream>>>(
        xh, Wh, bq, bk, bv, rcos, rsin, q_h, k_h, v_hT);
    attn<<<dim3(52, NHEAD), 256, 25600, stream>>>(q_h, k_h, v_hT, aout);
    cvt_wo<<<dim3(128), 256, 0, stream>>>(Wo, Woh);
    gemm_out<<<dim3(26, 15), 256, 16384, stream>>>(aout, Woh, bo, (float*)d_out);
}